// Round 10
// baseline (5393.371 us; speedup 1.0000x reference)
//
#include <hip/hip_runtime.h>

typedef unsigned short u16;
typedef unsigned int   u32;
typedef __attribute__((ext_vector_type(4))) float floatx4;
typedef __attribute__((ext_vector_type(4))) u32  u32x4;
typedef __attribute__((ext_vector_type(8))) short short8;

#define B_SZ  128
#define L_SEQ 1024
#define V_SZ  32
#define E_SZ  256
#define H_SZ  1024

#define N_GROUPS     8
#define WG_PER_GROUP 8                   // 8 WGs x 128 cols = 1024
#define N_BLOCKS     (N_GROUPS * WG_PER_GROUP)   // 64
#define LOGIT_BASE   (B_SZ * L_SEQ * V_SZ)

// workspace layout (bytes)
#define BAR_BYTES  8192
#define FLAG_OFF   (BAR_BYTES - 8)       // dtype flag
#define P_OFF      BAR_BYTES
#define P_BYTES    (V_SZ * H_SZ * 4)
#define HBUF_OFF   (P_OFF + P_BYTES)
#define HBUF_BYTES (N_GROUPS * 2 * 16 * H_SZ * 4)   // 1 MB: tagged u32 h

#define MFMA16x16x32(a, b, c) __builtin_amdgcn_mfma_f32_16x16x32_bf16(a, b, c, 0, 0, 0)

__device__ inline float b2f(u16 u) {
    union { unsigned i; float f; } x; x.i = ((unsigned)u) << 16; return x.f;
}
__device__ inline u16 f2b(float f) {
    unsigned u = __float_as_uint(f);
    return (u16)((u + 0x7FFFu + ((u >> 16) & 1u)) >> 16);   // RNE
}
__device__ inline float ldf(const void* p, long i, int isf32) {
    return isf32 ? ((const float*)p)[i] : b2f(((const u16*)p)[i]);
}
__device__ inline u16 ldb(const void* p, long i, int isf32) {
    return isf32 ? f2b(((const float*)p)[i]) : ((const u16*)p)[i];
}

// ---------------------------------------------------------------------------
// Tagged h exchange (R9 post-mortem): h element = (bf16<<16)|epoch16. The
// reader's data loads ARE the synchronization: retry until all 64 tags match.
// Removes drain + flag-store + poll from the serial chain — writer store-acks
// and reader loads overlap in one vmcnt wait (max, not sum). Tags in a given
// buffer go 1,3,5,... (<= 1025, no aliasing); 0xAAAA poison never matches.
// Early-clobber outputs (R8 post-mortem: address/output overlap = mem fault).
// ---------------------------------------------------------------------------
__device__ inline void load_tagged(const u32* base, u32 tag, short8 afr[8]) {
    u32x4 q0,q1,q2,q3,q4,q5,q6,q7,q8,q9,q10,q11,q12,q13,q14,q15;
    long guard = 0;
    for (;;) {
        asm volatile(
            "global_load_dwordx4 %0,  %16, off offset:0   sc0 sc1\n\t"
            "global_load_dwordx4 %1,  %16, off offset:16  sc0 sc1\n\t"
            "global_load_dwordx4 %2,  %16, off offset:128 sc0 sc1\n\t"
            "global_load_dwordx4 %3,  %16, off offset:144 sc0 sc1\n\t"
            "global_load_dwordx4 %4,  %16, off offset:256 sc0 sc1\n\t"
            "global_load_dwordx4 %5,  %16, off offset:272 sc0 sc1\n\t"
            "global_load_dwordx4 %6,  %16, off offset:384 sc0 sc1\n\t"
            "global_load_dwordx4 %7,  %16, off offset:400 sc0 sc1\n\t"
            "global_load_dwordx4 %8,  %16, off offset:512 sc0 sc1\n\t"
            "global_load_dwordx4 %9,  %16, off offset:528 sc0 sc1\n\t"
            "global_load_dwordx4 %10, %16, off offset:640 sc0 sc1\n\t"
            "global_load_dwordx4 %11, %16, off offset:656 sc0 sc1\n\t"
            "global_load_dwordx4 %12, %16, off offset:768 sc0 sc1\n\t"
            "global_load_dwordx4 %13, %16, off offset:784 sc0 sc1\n\t"
            "global_load_dwordx4 %14, %16, off offset:896 sc0 sc1\n\t"
            "global_load_dwordx4 %15, %16, off offset:912 sc0 sc1\n\t"
            "s_waitcnt vmcnt(0)"
            : "=&v"(q0), "=&v"(q1), "=&v"(q2),  "=&v"(q3),
              "=&v"(q4), "=&v"(q5), "=&v"(q6),  "=&v"(q7),
              "=&v"(q8), "=&v"(q9), "=&v"(q10), "=&v"(q11),
              "=&v"(q12),"=&v"(q13),"=&v"(q14), "=&v"(q15)
            : "v"(base)
            : "memory");
        u32 m = 0;
#define CHK(q) m |= (q[0] ^ tag) | (q[1] ^ tag) | (q[2] ^ tag) | (q[3] ^ tag)
        CHK(q0); CHK(q1); CHK(q2);  CHK(q3);  CHK(q4);  CHK(q5);  CHK(q6);  CHK(q7);
        CHK(q8); CHK(q9); CHK(q10); CHK(q11); CHK(q12); CHK(q13); CHK(q14); CHK(q15);
#undef CHK
        if (!__any((int)((m & 0xFFFFu) != 0))) break;
        if (++guard > 300000L) break;    // fail visibly, never hang
    }
#define UNP(kk, qa, qb) { u16* t = (u16*)&afr[kk]; \
        t[0]=(u16)(qa[0]>>16); t[1]=(u16)(qa[1]>>16); t[2]=(u16)(qa[2]>>16); t[3]=(u16)(qa[3]>>16); \
        t[4]=(u16)(qb[0]>>16); t[5]=(u16)(qb[1]>>16); t[6]=(u16)(qb[2]>>16); t[7]=(u16)(qb[3]>>16); }
    UNP(0,q0,q1) UNP(1,q2,q3) UNP(2,q4,q5)  UNP(3,q6,q7)
    UNP(4,q8,q9) UNP(5,q10,q11) UNP(6,q12,q13) UNP(7,q14,q15)
#undef UNP
}

__device__ inline void store_tagged(u32* p, const float h[8], u32 tag) {
    u32x4 d0, d1;
    #pragma unroll
    for (int j = 0; j < 4; ++j) d0[j] = ((u32)f2b(h[j])     << 16) | tag;
    #pragma unroll
    for (int j = 0; j < 4; ++j) d1[j] = ((u32)f2b(h[4 + j]) << 16) | tag;
    asm volatile(
        "global_store_dwordx4 %0, %1, off sc0 sc1\n\t"
        "global_store_dwordx4 %0, %2, off offset:16 sc0 sc1"
        :: "v"(p), "v"(d0), "v"(d1) : "memory");
}

// ---------------------------------------------------------------------------
__global__ void detect_dtype(const u16* __restrict__ emb, const int* __restrict__ xi,
                             int* __restrict__ flag) {
    float v = b2f(emb[threadIdx.x]);
    if (!(fabsf(v) <= 1.0e6f)) atomicOr(flag, 1);
    if (xi[2 * threadIdx.x + 1] != 0) atomicOr(flag, 2);
}

__global__ void precompute_P(const void* __restrict__ emb, const void* __restrict__ We,
                             const void* __restrict__ bh, float* __restrict__ P,
                             const int* __restrict__ flag) {
    const int isf32 = *flag & 1;
    int o = blockIdx.x * 256 + threadIdx.x;
    int v = o >> 10, h = o & (H_SZ - 1);
    float acc = ldf(bh, h, isf32);
    for (int e = 0; e < E_SZ; ++e)
        acc += ldf(emb, v * E_SZ + e, isf32) * ldf(We, (long)e * H_SZ + h, isf32);
    P[o] = acc;
}

// ---------------------------------------------------------------------------
// Persistent RNN. 64 WGs x 256 thr. group g=blockIdx&7 (16 batches),
// wg=blockIdx>>3 owns cols [128wg,128wg+128): whf[8][8] stationary in regs.
// Wave = K-quarter; 64 MFMAs/wave/step; 4-way LDS reduce (b-stride 20).
// Sync = epoch-tagged h data itself (no flags, no drain, no poll).
// ---------------------------------------------------------------------------
__global__ void __launch_bounds__(256, 1) rnn_kernel(
    const void* __restrict__ xp, const void* __restrict__ hidden,
    const void* __restrict__ Wh, const void* __restrict__ Wo,
    const void* __restrict__ bo, const float* __restrict__ P,
    u32* __restrict__ hbuf, float* __restrict__ out,
    const int* __restrict__ flag)
{
    __shared__ __align__(16) float red[12800];   // 50 KB

    const int fl    = *flag;
    const int isf32 = fl & 1;
    const int xi64  = !(fl & 2);
    const int g     = blockIdx.x & 7;
    const int wg    = blockIdx.x >> 3;
    const int col0  = wg * 128;
    const int b0    = g * 16;
    const int tid   = threadIdx.x;
    const int wave  = tid >> 6;
    const int lane  = tid & 63;
    const int lrow  = lane & 15;
    const int quad  = lane >> 4;
    const int kwave = wave * 256;

    const int* x32       = (const int*)xp;
    const long long* x64 = (const long long*)xp;

    u32* hb0 = hbuf + g * (2 * 16 * H_SZ);
    u32* hb1 = hb0 + 16 * H_SZ;

    // ---- stationary weights: whf 256 + wof 64 reg-equivalents (cached loads) ----
    short8 whf[8][8], wof[2][8];
    #pragma unroll
    for (int kk = 0; kk < 8; ++kk) {
        const int kb = kwave + kk * 32 + quad * 8;
        #pragma unroll
        for (int j = 0; j < 8; ++j) {
            #pragma unroll
            for (int nt = 0; nt < 8; ++nt)
                whf[nt][kk][j] = (short)ldb(Wh, (long)(kb + j) * H_SZ + col0 + nt * 16 + lrow, isf32);
            wof[0][kk][j] = (short)ldb(Wo, (long)(kb + j) * V_SZ + lrow, isf32);
            wof[1][kk][j] = (short)ldb(Wo, (long)(kb + j) * V_SZ + 16 + lrow, isf32);
        }
    }

    const int bq = tid >> 4;             // batch row 0..15
    const int c0 = (tid & 15) * 8;       // 8 consecutive cols [c0, c0+8)
    const float bov0 = ldf(bo, (tid & 15) * 2, isf32);
    const float bov1 = ldf(bo, (tid & 15) * 2 + 1, isf32);

    // ---- init h_0 slice, tagged epoch 1 (readers poll the data; no barrier) ----
    {
        float h0[8];
        #pragma unroll
        for (int j = 0; j < 8; ++j)
            h0[j] = ldf(hidden, (long)(b0 + bq) * H_SZ + col0 + c0 + j, isf32);
        store_tagged(hb0 + bq * H_SZ + col0 + c0, h0, 1u);
    }

    for (int s = 0; s < L_SEQ; ++s) {
        const u32* hc = (s & 1) ? hb1 : hb0;
        u32*       hn = (s & 1) ? hb0 : hb1;
        const bool do_logit = (wg == (s & 7));

        // ---- prefetch x, P (independent of h; overlap the tagged-load RT) ----
        long xoff = (long)(b0 + bq) * L_SEQ + s;
        int xv = xi64 ? (int)x64[xoff] : x32[xoff];
        const floatx4* pp = (const floatx4*)(P + (long)xv * H_SZ + col0 + c0);
        floatx4 pv0 = pp[0], pv1 = pp[1];

        // ---- A-frags: tagged loads (sync + data in one RT) ----
        short8 afr[8];
        load_tagged(hc + lrow * H_SZ + kwave + quad * 8, (u32)(s + 1), afr);

        // ---- MFMA: 8 col-tiles (+2 logit tiles on duty WG) ----
        floatx4 acc[8] = {};
        floatx4 aL0 = {0,0,0,0}, aL1 = {0,0,0,0};
        #pragma unroll
        for (int kk = 0; kk < 8; ++kk) {
            #pragma unroll
            for (int nt = 0; nt < 8; ++nt)
                acc[nt] = MFMA16x16x32(afr[kk], whf[nt][kk], acc[nt]);
            if (do_logit) {
                aL0 = MFMA16x16x32(afr[kk], wof[0][kk], aL0);
                aL1 = MFMA16x16x32(afr[kk], wof[1][kk], aL1);
            }
        }
        // C layout: col = lane&15, row = quad*4 + r
        #pragma unroll
        for (int nt = 0; nt < 8; ++nt)
            #pragma unroll
            for (int r = 0; r < 4; ++r)
                red[wave * 2560 + nt * 320 + (quad * 4 + r) * 20 + lrow] = acc[nt][r];
        if (do_logit)
            #pragma unroll
            for (int r = 0; r < 4; ++r) {
                red[10240 + wave * 640 +       (quad * 4 + r) * 20 + lrow] = aL0[r];
                red[10240 + wave * 640 + 320 + (quad * 4 + r) * 20 + lrow] = aL1[r];
            }
        __syncthreads();

        // ---- epilogue: h_{s+1} = tanh(P[x_s] + h_s @ Wh), tagged store s+2 ----
        {
            const int base = (c0 >> 4) * 320 + bq * 20 + (c0 & 15);
            floatx4 s0 = {0,0,0,0}, s1 = {0,0,0,0};
            #pragma unroll
            for (int w = 0; w < 4; ++w) {
                s0 += *(const floatx4*)&red[w * 2560 + base];
                s1 += *(const floatx4*)&red[w * 2560 + base + 4];
            }
            float h[8];
            #pragma unroll
            for (int j = 0; j < 4; ++j) h[j]     = tanhf(s0[j] + pv0[j]);
            #pragma unroll
            for (int j = 0; j < 4; ++j) h[4 + j] = tanhf(s1[j] + pv1[j]);
            store_tagged(hn + bq * H_SZ + col0 + c0, h, (u32)(s + 2));
            if (s == L_SEQ - 1) {
                float* op = out + LOGIT_BASE + (long)(b0 + bq) * H_SZ + col0 + c0;
                ((floatx4*)op)[0] = floatx4{h[0], h[1], h[2], h[3]};
                ((floatx4*)op)[1] = floatx4{h[4], h[5], h[6], h[7]};
            }
        }

        // ---- duty WG: logits[s-1] (red already synced; off critical path) ----
        if (do_logit && s >= 1) {
            int v0 = (tid & 15) * 2;
            int lb = 10240 + (v0 >> 4) * 320 + bq * 20 + (v0 & 15);
            float q0 = 0.f, q1 = 0.f;
            #pragma unroll
            for (int w = 0; w < 4; ++w) {
                q0 += red[lb + w * 640];
                q1 += red[lb + w * 640 + 1];
            }
            long ob = ((long)(b0 + bq) * L_SEQ + (s - 1)) * V_SZ + v0;
            out[ob]     = q0 + bov0;
            out[ob + 1] = q1 + bov1;
        }
        __syncthreads();   // red WAR: next iter's writes vs this iter's reads
    }

    // ---- final logits t = L-1 from h_L (hb0, tag L+1), WG0 of each group ----
    if (wg == 0) {
        short8 afr[8];
        load_tagged(hb0 + lrow * H_SZ + kwave + quad * 8, (u32)(L_SEQ + 1), afr);
        floatx4 aL0 = {0,0,0,0}, aL1 = {0,0,0,0};
        #pragma unroll
        for (int kk = 0; kk < 8; ++kk) {
            aL0 = MFMA16x16x32(afr[kk], wof[0][kk], aL0);
            aL1 = MFMA16x16x32(afr[kk], wof[1][kk], aL1);
        }
        #pragma unroll
        for (int r = 0; r < 4; ++r) {
            red[10240 + wave * 640 +       (quad * 4 + r) * 20 + lrow] = aL0[r];
            red[10240 + wave * 640 + 320 + (quad * 4 + r) * 20 + lrow] = aL1[r];
        }
        __syncthreads();
        {
            int v0 = (tid & 15) * 2;
            int lb = 10240 + (v0 >> 4) * 320 + bq * 20 + (v0 & 15);
            float q0 = 0.f, q1 = 0.f;
            #pragma unroll
            for (int w = 0; w < 4; ++w) {
                q0 += red[lb + w * 640];
                q1 += red[lb + w * 640 + 1];
            }
            long ob = ((long)(b0 + bq) * L_SEQ + (L_SEQ - 1)) * V_SZ + v0;
            out[ob]     = q0 + bov0;
            out[ob + 1] = q1 + bov1;
        }
    }
}

// ---------------------------------------------------------------------------
extern "C" void kernel_launch(void* const* d_in, const int* in_sizes, int n_in,
                              void* d_out, int out_size, void* d_ws, size_t ws_size,
                              hipStream_t stream) {
    (void)in_sizes; (void)n_in; (void)out_size; (void)ws_size;
    const void* x      = d_in[0];
    const void* hidden = d_in[1];
    const void* emb    = d_in[2];
    const void* We     = d_in[3];
    const void* Wh     = d_in[4];
    const void* bh     = d_in[5];
    const void* Wo     = d_in[6];
    const void* bo     = d_in[7];
    float* out = (float*)d_out;

    char* ws = (char*)d_ws;
    int*   flag = (int*)(ws + FLAG_OFF);
    float* P    = (float*)(ws + P_OFF);
    u32*   hbuf = (u32*)(ws + HBUF_OFF);

    // zero the dtype flag; hbuf stays 0xAA-poisoned (tag 0xAAAA never matches)
    hipMemsetAsync(ws, 0, BAR_BYTES, stream);

    detect_dtype<<<dim3(1), dim3(256), 0, stream>>>((const u16*)emb, (const int*)x, flag);
    precompute_P<<<dim3(128), dim3(256), 0, stream>>>(emb, We, bh, P, flag);

    rnn_kernel<<<dim3(N_BLOCKS), dim3(256), 0, stream>>>(
        x, hidden, Wh, Wo, bo, P, hbuf, out, flag);
}

// Round 13
// 4180.857 us; speedup vs baseline: 1.2900x; 1.2900x over previous
//
#include <hip/hip_runtime.h>

typedef unsigned short u16;
typedef unsigned int   u32;
typedef __attribute__((ext_vector_type(4))) float floatx4;
typedef __attribute__((ext_vector_type(4))) u32  u32x4;
typedef __attribute__((ext_vector_type(8))) short short8;

#define B_SZ  128
#define L_SEQ 1024
#define V_SZ  32
#define E_SZ  256
#define H_SZ  1024

#define N_GROUPS     8
#define WG_PER_GROUP 8                   // 8 WGs x 128 cols = 1024
#define N_BLOCKS     (N_GROUPS * WG_PER_GROUP)   // 64
#define LOGIT_BASE   (B_SZ * L_SEQ * V_SZ)

// workspace layout (bytes)
#define BAR_BYTES  8192
#define FLAG_OFF   (BAR_BYTES - 8)       // dtype flag
#define P_OFF      BAR_BYTES
#define P_BYTES    (V_SZ * H_SZ * 4)
#define HBUF_OFF   (P_OFF + P_BYTES)
#define HBUF_BYTES (N_GROUPS * 2 * 16 * H_SZ * 2)

#define MFMA16x16x32(a, b, c) __builtin_amdgcn_mfma_f32_16x16x32_bf16(a, b, c, 0, 0, 0)

__device__ inline float b2f(u16 u) {
    union { unsigned i; float f; } x; x.i = ((unsigned)u) << 16; return x.f;
}
__device__ inline u16 f2b(float f) {
    unsigned u = __float_as_uint(f);
    return (u16)((u + 0x7FFFu + ((u >> 16) & 1u)) >> 16);   // RNE
}
__device__ inline float ldf(const void* p, long i, int isf32) {
    return isf32 ? ((const float*)p)[i] : b2f(((const u16*)p)[i]);
}
__device__ inline u16 ldb(const void* p, long i, int isf32) {
    return isf32 ? f2b(((const float*)p)[i]) : ((const u16*)p)[i];
}

// ---------------------------------------------------------------------------
// Coherent exchange: sc0+sc1 global ops ONLY (LLC scope). R11/R12 post-mortem:
// sc0-only "XCD-local" polling can read stale L1 in steady state -> per-step
// guard timeouts -> minutes-long run -> harness kill. Never again.
// Early-clobber asm outputs (R8 post-mortem: addr/output overlap = mem fault).
// ---------------------------------------------------------------------------
__device__ inline u32 fload(const u32* p) {
    u32 v;
    asm volatile("global_load_dword %0, %1, off sc0 sc1\n\ts_waitcnt vmcnt(0)"
                 : "=&v"(v) : "v"(p) : "memory");
    return v;
}
__device__ inline void fstore(u32* p, u32 v) {
    asm volatile("global_store_dword %0, %1, off sc0 sc1" :: "v"(p), "v"(v) : "memory");
}
__device__ inline void ld_row16(const u16* abase, short8 afr[8]) {
    u32x4 a0, a1, a2, a3, a4, a5, a6, a7;
    asm volatile(
        "global_load_dwordx4 %0, %8, off offset:0   sc0 sc1\n\t"
        "global_load_dwordx4 %1, %8, off offset:64  sc0 sc1\n\t"
        "global_load_dwordx4 %2, %8, off offset:128 sc0 sc1\n\t"
        "global_load_dwordx4 %3, %8, off offset:192 sc0 sc1\n\t"
        "global_load_dwordx4 %4, %8, off offset:256 sc0 sc1\n\t"
        "global_load_dwordx4 %5, %8, off offset:320 sc0 sc1\n\t"
        "global_load_dwordx4 %6, %8, off offset:384 sc0 sc1\n\t"
        "global_load_dwordx4 %7, %8, off offset:448 sc0 sc1\n\t"
        "s_waitcnt vmcnt(0)"
        : "=&v"(a0), "=&v"(a1), "=&v"(a2), "=&v"(a3),
          "=&v"(a4), "=&v"(a5), "=&v"(a6), "=&v"(a7)
        : "v"(abase)
        : "memory");
    union { u32x4 v; short8 s; } u;
    u.v = a0; afr[0] = u.s; u.v = a1; afr[1] = u.s;
    u.v = a2; afr[2] = u.s; u.v = a3; afr[3] = u.s;
    u.v = a4; afr[4] = u.s; u.v = a5; afr[5] = u.s;
    u.v = a6; afr[6] = u.s; u.v = a7; afr[7] = u.s;
}
__device__ inline void st_row16(u32* p, u32x4 d) {
    asm volatile("global_store_dwordx4 %0, %1, off sc0 sc1" :: "v"(p), "v"(d) : "memory");
}

// ---------------------------------------------------------------------------
__global__ void detect_dtype(const u16* __restrict__ emb, const int* __restrict__ xi,
                             int* __restrict__ flag) {
    float v = b2f(emb[threadIdx.x]);
    if (!(fabsf(v) <= 1.0e6f)) atomicOr(flag, 1);
    if (xi[2 * threadIdx.x + 1] != 0) atomicOr(flag, 2);
}

__global__ void precompute_P(const void* __restrict__ emb, const void* __restrict__ We,
                             const void* __restrict__ bh, float* __restrict__ P,
                             const int* __restrict__ flag) {
    const int isf32 = *flag & 1;
    int o = blockIdx.x * 256 + threadIdx.x;
    int v = o >> 10, h = o & (H_SZ - 1);
    float acc = ldf(bh, h, isf32);
    for (int e = 0; e < E_SZ; ++e)
        acc += ldf(emb, v * E_SZ + e, isf32) * ldf(We, (long)e * H_SZ + h, isf32);
    P[o] = acc;
}

// ---------------------------------------------------------------------------
// Persistent RNN — the R9 structure (passed, 4321 us), LLC-scope exchange.
// 64 WGs x 256 thr. group g=blockIdx&7 (16 batches), wg=blockIdx>>3 owns
// cols [128wg,128wg+128): whf[8][8] stationary in VGPRs. Wave = K-quarter;
// 64 MFMAs/wave/step; 4-way LDS reduce (b-stride 20). Epoch-flag barrier,
// duty-rotated logits after the flag publish (off the critical path).
// Chain floor: detect + A-load RT + compute + drain RT + flag ~= 3.7 us/step.
// ---------------------------------------------------------------------------
__global__ void __launch_bounds__(256, 1) rnn_kernel(
    const void* __restrict__ xp, const void* __restrict__ hidden,
    const void* __restrict__ Wh, const void* __restrict__ Wo,
    const void* __restrict__ bo, const float* __restrict__ P,
    u32* __restrict__ bars, u16* __restrict__ hbuf, float* __restrict__ out,
    const int* __restrict__ flag)
{
    __shared__ __align__(16) float red[12800];   // 50 KB

    const int fl    = *flag;
    const int isf32 = fl & 1;
    const int xi64  = !(fl & 2);
    const int g     = blockIdx.x & 7;
    const int wg    = blockIdx.x >> 3;
    const int col0  = wg * 128;
    const int b0    = g * 16;
    const int tid   = threadIdx.x;
    const int wave  = tid >> 6;
    const int lane  = tid & 63;
    const int lrow  = lane & 15;
    const int quad  = lane >> 4;
    const int kwave = wave * 256;

    const int* x32       = (const int*)xp;
    const long long* x64 = (const long long*)xp;

    u32* flags = bars + g * 8;                       // 8 flags, one 32B line
    u16* hb0 = hbuf + g * (2 * 16 * H_SZ);
    u16* hb1 = hb0 + 16 * H_SZ;

    // ---- stationary weights (cached loads, L2-warm forever) ----
    short8 whf[8][8], wof[2][8];
    #pragma unroll
    for (int kk = 0; kk < 8; ++kk) {
        const int kb = kwave + kk * 32 + quad * 8;
        #pragma unroll
        for (int j = 0; j < 8; ++j) {
            #pragma unroll
            for (int nt = 0; nt < 8; ++nt)
                whf[nt][kk][j] = (short)ldb(Wh, (long)(kb + j) * H_SZ + col0 + nt * 16 + lrow, isf32);
            wof[0][kk][j] = (short)ldb(Wo, (long)(kb + j) * V_SZ + lrow, isf32);
            wof[1][kk][j] = (short)ldb(Wo, (long)(kb + j) * V_SZ + 16 + lrow, isf32);
        }
    }

    const int bq = tid >> 4;             // batch row 0..15
    const int c0 = (tid & 15) * 8;       // 8 consecutive cols [c0, c0+8)
    const float bov0 = ldf(bo, (tid & 15) * 2, isf32);
    const float bov1 = ldf(bo, (tid & 15) * 2 + 1, isf32);

    // ---- init h_0 slice, drain, flag epoch 1 ----
    {
        u32x4 d;
        #pragma unroll
        for (int p = 0; p < 4; ++p) {
            u16 lo = ldb(hidden, (long)(b0 + bq) * H_SZ + col0 + c0 + 2 * p, isf32);
            u16 hi = ldb(hidden, (long)(b0 + bq) * H_SZ + col0 + c0 + 2 * p + 1, isf32);
            d[p] = (u32)lo | ((u32)hi << 16);
        }
        st_row16((u32*)(hb0 + bq * H_SZ + col0 + c0), d);
    }
    __builtin_amdgcn_s_waitcnt(0);
    __syncthreads();
    if (tid == 0) fstore(flags + wg, 1u);

    for (int s = 0; s < L_SEQ; ++s) {
        const u16* hc = (s & 1) ? hb1 : hb0;
        u16*       hn = (s & 1) ? hb0 : hb1;
        const bool do_logit = (wg == (s & 7));
        const u32 target = (u32)(s + 1);

        // ---- prefetch x, P (independent of h — hoisted above the poll) ----
        long xoff = (long)(b0 + bq) * L_SEQ + s;
        int xv = xi64 ? (int)x64[xoff] : x32[xoff];
        const floatx4* pp = (const floatx4*)(P + (long)xv * H_SZ + col0 + c0);
        floatx4 pv0 = pp[0], pv1 = pp[1];

        // ---- poll all 8 epoch flags (one 32B line, coalesced) ----
        {
            long guard = 0;
            u32 f = fload(flags + (lane & 7));
            while (__any((int)(f < target))) {
                __builtin_amdgcn_s_sleep(1);
                f = fload(flags + (lane & 7));
                if (++guard > 500000L) break;   // fail visibly + fast, never hang
            }
        }

        // ---- A-frags: 8 x 16B coherent loads ----
        short8 afr[8];
        ld_row16(hc + lrow * H_SZ + kwave + quad * 8, afr);

        // ---- MFMA: 8 col-tiles (+2 logit tiles on duty WG) ----
        floatx4 acc[8] = {};
        floatx4 aL0 = {0,0,0,0}, aL1 = {0,0,0,0};
        #pragma unroll
        for (int kk = 0; kk < 8; ++kk) {
            #pragma unroll
            for (int nt = 0; nt < 8; ++nt)
                acc[nt] = MFMA16x16x32(afr[kk], whf[nt][kk], acc[nt]);
            if (do_logit) {
                aL0 = MFMA16x16x32(afr[kk], wof[0][kk], aL0);
                aL1 = MFMA16x16x32(afr[kk], wof[1][kk], aL1);
            }
        }
        // C layout: col = lane&15, row = quad*4 + r
        #pragma unroll
        for (int nt = 0; nt < 8; ++nt)
            #pragma unroll
            for (int r = 0; r < 4; ++r)
                red[wave * 2560 + nt * 320 + (quad * 4 + r) * 20 + lrow] = acc[nt][r];
        if (do_logit)
            #pragma unroll
            for (int r = 0; r < 4; ++r) {
                red[10240 + wave * 640 +       (quad * 4 + r) * 20 + lrow] = aL0[r];
                red[10240 + wave * 640 + 320 + (quad * 4 + r) * 20 + lrow] = aL1[r];
            }
        __syncthreads();

        // ---- epilogue: h_{s+1} = tanh(P[x_s] + h_s @ Wh), one 16B h-store ----
        {
            const int base = (c0 >> 4) * 320 + bq * 20 + (c0 & 15);
            floatx4 s0 = {0,0,0,0}, s1 = {0,0,0,0};
            #pragma unroll
            for (int w = 0; w < 4; ++w) {
                s0 += *(const floatx4*)&red[w * 2560 + base];
                s1 += *(const floatx4*)&red[w * 2560 + base + 4];
            }
            float h[8];
            #pragma unroll
            for (int j = 0; j < 4; ++j) h[j]     = tanhf(s0[j] + pv0[j]);
            #pragma unroll
            for (int j = 0; j < 4; ++j) h[4 + j] = tanhf(s1[j] + pv1[j]);
            u32x4 d;
            #pragma unroll
            for (int p = 0; p < 4; ++p)
                d[p] = (u32)f2b(h[2 * p]) | ((u32)f2b(h[2 * p + 1]) << 16);
            st_row16((u32*)(hn + bq * H_SZ + col0 + c0), d);
            if (s == L_SEQ - 1) {
                float* op = out + LOGIT_BASE + (long)(b0 + bq) * H_SZ + col0 + c0;
                ((floatx4*)op)[0] = floatx4{h[0], h[1], h[2], h[3]};
                ((floatx4*)op)[1] = floatx4{h[4], h[5], h[6], h[7]};
            }
        }

        // ---- drain h-stores, publish epoch ----
        __builtin_amdgcn_s_waitcnt(0);
        __syncthreads();
        if (tid == 0) fstore(flags + wg, (u32)(s + 2));

        // ---- duty WG: logits[s-1] off the critical path ----
        if (do_logit && s >= 1) {
            int v0 = (tid & 15) * 2;
            int lb = 10240 + (v0 >> 4) * 320 + bq * 20 + (v0 & 15);
            float q0 = 0.f, q1 = 0.f;
            #pragma unroll
            for (int w = 0; w < 4; ++w) {
                q0 += red[lb + w * 640];
                q1 += red[lb + w * 640 + 1];
            }
            long ob = ((long)(b0 + bq) * L_SEQ + (s - 1)) * V_SZ + v0;
            out[ob]     = q0 + bov0;
            out[ob + 1] = q1 + bov1;
        }
    }

    // ---- final logits t = L-1 from h_L (hb0: L even), WG0 of each group ----
    if (wg == 0) {
        {
            long guard = 0;
            u32 f = fload(flags + (lane & 7));
            while (__any((int)(f < (u32)(L_SEQ + 1)))) {
                __builtin_amdgcn_s_sleep(1);
                f = fload(flags + (lane & 7));
                if (++guard > 500000L) break;
            }
        }
        short8 afr[8];
        ld_row16(hb0 + lrow * H_SZ + kwave + quad * 8, afr);
        floatx4 aL0 = {0,0,0,0}, aL1 = {0,0,0,0};
        #pragma unroll
        for (int kk = 0; kk < 8; ++kk) {
            aL0 = MFMA16x16x32(afr[kk], wof[0][kk], aL0);
            aL1 = MFMA16x16x32(afr[kk], wof[1][kk], aL1);
        }
        #pragma unroll
        for (int r = 0; r < 4; ++r) {
            red[10240 + wave * 640 +       (quad * 4 + r) * 20 + lrow] = aL0[r];
            red[10240 + wave * 640 + 320 + (quad * 4 + r) * 20 + lrow] = aL1[r];
        }
        __syncthreads();
        {
            int v0 = (tid & 15) * 2;
            int lb = 10240 + (v0 >> 4) * 320 + bq * 20 + (v0 & 15);
            float q0 = 0.f, q1 = 0.f;
            #pragma unroll
            for (int w = 0; w < 4; ++w) {
                q0 += red[lb + w * 640];
                q1 += red[lb + w * 640 + 1];
            }
            long ob = ((long)(b0 + bq) * L_SEQ + (L_SEQ - 1)) * V_SZ + v0;
            out[ob]     = q0 + bov0;
            out[ob + 1] = q1 + bov1;
        }
    }
}

// ---------------------------------------------------------------------------
extern "C" void kernel_launch(void* const* d_in, const int* in_sizes, int n_in,
                              void* d_out, int out_size, void* d_ws, size_t ws_size,
                              hipStream_t stream) {
    (void)in_sizes; (void)n_in; (void)out_size; (void)ws_size;
    const void* x      = d_in[0];
    const void* hidden = d_in[1];
    const void* emb    = d_in[2];
    const void* We     = d_in[3];
    const void* Wh     = d_in[4];
    const void* bh     = d_in[5];
    const void* Wo     = d_in[6];
    const void* bo     = d_in[7];
    float* out = (float*)d_out;

    char* ws = (char*)d_ws;
    u32*   bars = (u32*)ws;
    int*   flag = (int*)(ws + FLAG_OFF);
    float* P    = (float*)(ws + P_OFF);
    u16*   hbuf = (u16*)(ws + HBUF_OFF);

    hipMemsetAsync(ws, 0, BAR_BYTES, stream);   // zero epoch flags + dtype flag

    detect_dtype<<<dim3(1), dim3(256), 0, stream>>>((const u16*)emb, (const int*)x, flag);
    precompute_P<<<dim3(128), dim3(256), 0, stream>>>(emb, We, bh, P, flag);

    rnn_kernel<<<dim3(N_BLOCKS), dim3(256), 0, stream>>>(
        x, hidden, Wh, Wo, bo, P, bars, hbuf, out, flag);
}